// Round 11
// baseline (391.677 us; speedup 1.0000x reference)
//
#include <hip/hip_runtime.h>
#include <hip/hip_bf16.h>

// HGNNP_GCN + ClusterNet forward, MI355X (round 11).
// R10 counters: k_fill2 47us, Occupancy 4.4% (grid=128 on 256 CUs; 50KB LDS),
// VALUBusy 1.4%, plus a dependent random rp[dd] read per element -> fill is
// latency-bound at half-GPU utilization. This round: 8 ranges x 6250 bins
// (25KB LDS, grid 512), hscan keeps chunk-prefix in place, fill cursors =
// prefix + rp[bin] staged via coalesced loads -> LDS atomicAdd returns the
// absolute csr position; no random global reads remain in the CSR build.

#define NN   50000   // nodes (= 8*6250)
#define NP   50048   // padded rows (782 * 64)
#define EE   800000  // directed edges (= 64*12500)
#define NINC 200000  // incidence entries (= 64*3125)
#define NEH  10000   // hyperedges (= 2*5000)
#define KCL  10      // clusters

// output element offsets (flat concat: mu | r | embeds | dist)
#define MU_OFF  0
#define R_OFF   640
#define EMB_OFF 500640
#define D_OFF   3700640

typedef __hip_bfloat16 bf16;
typedef unsigned short u16;
typedef unsigned int   u32;
typedef __attribute__((ext_vector_type(8))) short short8;
typedef __attribute__((ext_vector_type(4))) float f32x4;

__device__ __forceinline__ float b2f(bf16 v){ return __bfloat162float(v); }
__device__ __forceinline__ float us2f(u16 u){ return __uint_as_float(((unsigned)u) << 16); }
__device__ __forceinline__ u16 f2bu(float f){
  unsigned u = __float_as_uint(f);
  return (u16)((u + 0x7fffu + ((u >> 16) & 1u)) >> 16);   // RNE
}
__device__ __forceinline__ bf16 f2b(float f){
  u16 r = f2bu(f);
  bf16 h;
  reinterpret_cast<u16&>(h) = r;
  return h;
}
__device__ __forceinline__ float ldf(const void* p, size_t i, int isbf){
  return isbf ? b2f(((const bf16*)p)[i]) : ((const float*)p)[i];
}
__device__ __forceinline__ void stf(void* p, size_t i, float v, int isbf){
  if (isbf) ((bf16*)p)[i] = f2b(v);
  else      ((float*)p)[i] = v;
}

// ---------------- dtype detector ----------------
__global__ void k_detect(const u16* __restrict__ xr, int* flag){
  __shared__ int bad;
  if (threadIdx.x == 0) bad = 0;
  __syncthreads();
  for (int i = threadIdx.x; i < 4096; i += 256){
    int e = (xr[i] >> 7) & 0xFF;
    if (e >= 0xEF) bad = 1;     // f32 low-halves have random exponents
  }
  __syncthreads();
  if (threadIdx.x == 0) *flag = bad ? 0 : 1;   // 1 = bf16, 0 = f32
}

// ---------------- input prep ----------------
__global__ void k_aconv(const void* __restrict__ x, u16* __restrict__ xb,
                        const int* __restrict__ flag){
  int i = blockIdx.x*256 + threadIdx.x;      // one ushort4 (4 elems)
  const int n4 = NN*256/4;
  if (i >= n4) return;
  ushort4 o;
  if (flag[0]){
    o = ((const ushort4*)x)[i];
  } else {
    float4 v = ((const float4*)x)[i];
    o = make_ushort4(f2bu(v.x), f2bu(v.y), f2bu(v.z), f2bu(v.w));
  }
  ((ushort4*)xb)[i] = o;
}

__global__ void k_wprep(const void* gW1, const void* hW1, const void* gW2, const void* hW2,
                        const void* gb1, const void* hb1, const void* gb2, const void* hb2,
                        u16* gW1t, u16* hW1t, u16* gW2t, u16* hW2t,
                        float* gb1f, float* hb1f, float* gb2f, float* hb2f,
                        const int* __restrict__ flag){
  const int isbf = flag[0];
  int i = blockIdx.x*256 + threadIdx.x;
  if (i < 256*128){                    // Wt[n][k] = W[k][n], 128x256
    int n = i >> 8, k = i & 255;
    gW1t[i] = f2bu(ldf(gW1, (size_t)k*128 + n, isbf));
    hW1t[i] = f2bu(ldf(hW1, (size_t)k*128 + n, isbf));
  }
  if (i < 64*128){                     // 64x128
    int n = i >> 7, k = i & 127;
    gW2t[i] = f2bu(ldf(gW2, (size_t)k*64 + n, isbf));
    hW2t[i] = f2bu(ldf(hW2, (size_t)k*64 + n, isbf));
  }
  if (i < 128){ gb1f[i] = ldf(gb1,i,isbf); hb1f[i] = ldf(hb1,i,isbf); }
  if (i < 64) { gb2f[i] = ldf(gb2,i,isbf); hb2f[i] = ldf(hb2,i,isbf); }
}

// ---------------- atomic-free CSR build (u32 bins, absolute cursors) ----------------
// grid = NRANGE*NCHUNK blocks; block (r,c) histograms keys of chunk c falling
// in bin range [r*BINS, (r+1)*BINS).
template<int BINS, int NCHUNK>
__global__ __launch_bounds__(256) void k_hist2(const int* __restrict__ key,
                                               u32* __restrict__ H, int chunk){
  __shared__ u32 hist[BINS];
  int r = blockIdx.x / NCHUNK, c = blockIdx.x % NCHUNK;
  for (int i = threadIdx.x; i < BINS; i += 256) hist[i] = 0;
  __syncthreads();
  int base = c*chunk, lo = r*BINS;
  for (int i = threadIdx.x; i < chunk; i += 256){
    int d = key[base+i] - lo;
    if ((unsigned)d < (unsigned)BINS) atomicAdd(&hist[d], 1u);
  }
  __syncthreads();
  u32* out = H + (size_t)blockIdx.x*BINS;
  for (int i = threadIdx.x; i < BINS; i += 256) out[i] = hist[i];
}

// per-bin prefix over chunks (in place -> prefix-before-chunk); emit totals
template<int BINS, int NCHUNK, int NRANGE>
__global__ void k_hscan2(u32* __restrict__ H, int* __restrict__ cnt){
  int t = blockIdx.x*256 + threadIdx.x;
  if (t >= NRANGE*BINS) return;
  int r = t / BINS, w = t % BINS;
  u32 run = 0;
  u32* col = H + (size_t)r*NCHUNK*BINS + w;
  for (int b = 0; b < NCHUNK; ++b){
    u32 v = col[(size_t)b*BINS];
    col[(size_t)b*BINS] = run;
    run += v;
  }
  cnt[t] = (int)run;
}

// fill: LDS cursors = chunk-prefix + rp[bin] (both coalesced); LDS atomicAdd
// returns the absolute csr position. No random global reads.
template<int BINS, int NCHUNK>
__global__ __launch_bounds__(256) void k_fill3(const int* __restrict__ key,
    const int* __restrict__ val, const u32* __restrict__ H,
    const int* __restrict__ rp, int* __restrict__ csr, int chunk){
  __shared__ u32 cur[BINS];
  int r = blockIdx.x / NCHUNK, c = blockIdx.x % NCHUNK;
  const u32* pre = H + (size_t)blockIdx.x*BINS;
  const int* rps = rp + r*BINS;
  for (int i = threadIdx.x; i < BINS; i += 256) cur[i] = pre[i] + (u32)rps[i];
  __syncthreads();
  int base = c*chunk, lo = r*BINS;
  for (int i = threadIdx.x; i < chunk; i += 256){
    int dd = key[base+i];
    int d = dd - lo;
    if ((unsigned)d < (unsigned)BINS){
      u32 pos = atomicAdd(&cur[d], 1u);
      csr[pos] = val[base+i];
    }
  }
}

__global__ void k_invs(const int* __restrict__ cg, const int* __restrict__ cv,
                       const int* __restrict__ ce,
                       float* dinv, float* invv, float* inve){
  int i = blockIdx.x*256 + threadIdx.x;
  if (i < NN){
    float d = 1.0f + (float)cg[i];     // self-loop included
    dinv[i] = rsqrtf(d);
    invv[i] = 1.0f / fmaxf((float)cv[i], 1.0f);
  } else if (i < NP){
    dinv[i] = 0.f;                     // pad rows
  }
  if (i < NEH) inve[i] = 1.0f / fmaxf((float)ce[i], 1.0f);
}

// ---------------- fused row-pointer scans (3 structures in one launch) ----------------
__global__ void k_scan1_all(const int* cg, const int* cv, const int* ce,
                            int* rp_g, int* rp_v, int* rp_e,
                            int* bs_g, int* bs_v, int* bs_e){
  const int blk = blockIdx.x;
  const int* in; int* out; int* bsum; int n; int lb;
  if (blk < 196){ in=cg; out=rp_g; bsum=bs_g; n=NN; lb=blk; }
  else if (blk < 392){ in=cv; out=rp_v; bsum=bs_v; n=NN; lb=blk-196; }
  else { in=ce; out=rp_e; bsum=bs_e; n=NEH; lb=blk-392; }
  __shared__ int s[256];
  int t = threadIdx.x, i = lb*256 + t;
  int v = (i < n) ? in[i] : 0;
  s[t] = v; __syncthreads();
  #pragma unroll
  for (int off = 1; off < 256; off <<= 1){
    int add = (t >= off) ? s[t-off] : 0;
    __syncthreads();
    s[t] += add;
    __syncthreads();
  }
  if (i < n) out[i] = s[t] - v;        // exclusive
  if (t == 255) bsum[lb] = s[255];
}

__global__ void k_scan2_all(int* bs_g, int* bs_v, int* bs_e){
  int* bsum; int nb;
  if (blockIdx.x == 0){ bsum = bs_g; nb = 196; }
  else if (blockIdx.x == 1){ bsum = bs_v; nb = 196; }
  else { bsum = bs_e; nb = 40; }
  __shared__ int s[256];
  int t = threadIdx.x;
  int v = (t < nb) ? bsum[t] : 0;
  s[t] = v; __syncthreads();
  #pragma unroll
  for (int off = 1; off < 256; off <<= 1){
    int add = (t >= off) ? s[t-off] : 0;
    __syncthreads();
    s[t] += add;
    __syncthreads();
  }
  if (t < nb) bsum[t] = s[t] - v;
}

__global__ void k_scan3_all(int* rp_g, int* rp_v, int* rp_e,
                            const int* bs_g, const int* bs_v, const int* bs_e){
  const int blk = blockIdx.x;
  int* rp; const int* bsum; int n; int lb;
  if (blk < 196){ rp=rp_g; bsum=bs_g; n=NN; lb=blk; }
  else if (blk < 392){ rp=rp_v; bsum=bs_v; n=NN; lb=blk-196; }
  else { rp=rp_e; bsum=bs_e; n=NEH; lb=blk-392; }
  int i = lb*256 + threadIdx.x;
  if (i < n) rp[i] += bsum[lb];
}

// ---------------- MFMA GEMM ----------------
template<int KDIM, int NCOL>
__global__ __launch_bounds__(256) void k_gemm_mfma(
    const u16* __restrict__ A, const u16* __restrict__ Wt,
    const float* __restrict__ bias, const float* __restrict__ rowscale,
    u16* __restrict__ C, int relu)
{
  constexpr int NT  = NCOL/16;
  constexpr int LDA = 40;
  __shared__ __align__(16) u16 Asl[64][LDA];
  __shared__ __align__(16) u16 Wsl[NCOL][LDA];
  const int tid  = threadIdx.x;
  const int wave = tid >> 6, lane = tid & 63;
  const int l15 = lane & 15, l4 = lane >> 4;
  const int row0 = blockIdx.x * 64;
  const int ar = tid >> 2, aq = tid & 3;
  constexpr int NW = NCOL*4/256;

  f32x4 acc[NT] = {};

  for (int kk = 0; kk < KDIM; kk += 32){
    {
      uint4 v = *(const uint4*)(A + (size_t)(row0 + ar)*KDIM + kk + aq*8);
      *(uint4*)&Asl[ar][aq*8] = v;
    }
    #pragma unroll
    for (int w2 = 0; w2 < NW; ++w2){
      int c = tid + w2*256;
      int n = c >> 2, q = c & 3;
      uint4 v = *(const uint4*)(Wt + (size_t)n*KDIM + kk + q*8);
      *(uint4*)&Wsl[n][q*8] = v;
    }
    __syncthreads();
    short8 af = *(const short8*)&Asl[wave*16 + l15][l4*8];
    #pragma unroll
    for (int t = 0; t < NT; ++t){
      short8 bf = *(const short8*)&Wsl[t*16 + l15][l4*8];
      acc[t] = __builtin_amdgcn_mfma_f32_16x16x32_bf16(af, bf, acc[t], 0, 0, 0);
    }
    __syncthreads();
  }

  #pragma unroll
  for (int t = 0; t < NT; ++t){
    int gcol = t*16 + l15;
    float b = bias ? bias[gcol] : 0.f;
    #pragma unroll
    for (int e = 0; e < 4; ++e){
      int grow = row0 + wave*16 + l4*4 + e;
      float v = acc[t][e] + b;
      if (relu) v = fmaxf(v, 0.f);
      if (rowscale) v *= rowscale[grow];
      C[(size_t)grow*NCOL + gcol] = f2bu(v);
    }
  }
}

// ---------------- unified gather: one wave per dst row ----------------
template<int F, bool OUTBF, bool SELF>
__global__ __launch_bounds__(256) void k_gather(
    const int* __restrict__ rp, const int* __restrict__ cnt,
    const int* __restrict__ csr, const float* __restrict__ scale,
    const u16* __restrict__ h, const float* __restrict__ bias,
    void* __restrict__ out, int relu)
{
  const int wave = threadIdx.x >> 6, lane = threadIdx.x & 63;
  const int d = blockIdx.x*4 + wave;
  const int k0 = rp[d], n = cnt[d];

  if constexpr (F == 128){
    const uint* h32 = (const uint*)h;
    float a0=0,a1=0,b0=0,b1=0,c0=0,c1=0,e0=0,e1=0;
    if (SELF){
      uint v = h32[(size_t)d*64 + lane];
      a0 = us2f((u16)v); a1 = us2f((u16)(v>>16));
    }
    for (int base = 0; base < n; base += 64){
      int mm = n - base; if (mm > 64) mm = 64;
      int idx = (lane < mm) ? csr[k0 + base + lane] : 0;
      int jj = 0;
      for (; jj + 4 <= mm; jj += 4){
        int s0=__shfl(idx,jj), s1=__shfl(idx,jj+1), s2=__shfl(idx,jj+2), s3=__shfl(idx,jj+3);
        uint v0 = h32[(size_t)s0*64 + lane];
        uint v1 = h32[(size_t)s1*64 + lane];
        uint v2 = h32[(size_t)s2*64 + lane];
        uint v3 = h32[(size_t)s3*64 + lane];
        a0 += us2f((u16)v0); a1 += us2f((u16)(v0>>16));
        b0 += us2f((u16)v1); b1 += us2f((u16)(v1>>16));
        c0 += us2f((u16)v2); c1 += us2f((u16)(v2>>16));
        e0 += us2f((u16)v3); e1 += us2f((u16)(v3>>16));
      }
      for (; jj < mm; ++jj){
        int s = __shfl(idx, jj);
        uint v = h32[(size_t)s*64 + lane];
        a0 += us2f((u16)v); a1 += us2f((u16)(v>>16));
      }
    }
    float sc = scale[d];
    float o0 = ((a0+b0)+(c0+e0))*sc;
    float o1 = ((a1+b1)+(c1+e1))*sc;
    if (bias){ o0 += bias[lane*2]; o1 += bias[lane*2+1]; }
    if (relu){ o0 = fmaxf(o0,0.f); o1 = fmaxf(o1,0.f); }
    if (OUTBF){
      ((uint*)out)[(size_t)d*64 + lane] = (uint)f2bu(o0) | ((uint)f2bu(o1) << 16);
    } else {
      ((float2*)out)[(size_t)d*64 + lane] = make_float2(o0, o1);
    }
  } else { // F == 64
    float a=0,b=0,c=0,e=0;
    if (SELF) a = us2f(h[(size_t)d*64 + lane]);
    for (int base = 0; base < n; base += 64){
      int mm = n - base; if (mm > 64) mm = 64;
      int idx = (lane < mm) ? csr[k0 + base + lane] : 0;
      int jj = 0;
      for (; jj + 4 <= mm; jj += 4){
        int s0=__shfl(idx,jj), s1=__shfl(idx,jj+1), s2=__shfl(idx,jj+2), s3=__shfl(idx,jj+3);
        a += us2f(h[(size_t)s0*64 + lane]);
        b += us2f(h[(size_t)s1*64 + lane]);
        c += us2f(h[(size_t)s2*64 + lane]);
        e += us2f(h[(size_t)s3*64 + lane]);
      }
      for (; jj < mm; ++jj){
        int s = __shfl(idx, jj);
        a += us2f(h[(size_t)s*64 + lane]);
      }
    }
    float o = ((a+b)+(c+e))*scale[d];
    if (bias) o += bias[lane];
    if (relu) o = fmaxf(o, 0.f);
    if (OUTBF) ((u16*)out)[(size_t)d*64 + lane] = f2bu(o);
    else       ((float*)out)[(size_t)d*64 + lane] = o;
  }
}

// ---------------- embeds + row normalize ----------------
__global__ void k_embeds(const float* __restrict__ x2, const float* __restrict__ x4,
                         void* __restrict__ out, float* __restrict__ data,
                         const int* __restrict__ flag){
  int row  = blockIdx.x*4 + (threadIdx.x >> 6);
  int lane = threadIdx.x & 63;
  if (row >= NN) return;
  size_t idx = (size_t)row*64 + lane;
  float v = 0.5f*(x2[idx] + x4[idx]);
  float ss = v*v;
  #pragma unroll
  for (int off=32; off>0; off>>=1) ss += __shfl_xor(ss, off);
  float inv = rsqrtf(ss);
  data[idx] = v*inv;
  stf(out, EMB_OFF + idx, v, flag[0]);
}

// ---------------- clustering ----------------
__global__ void k_mu_init(const float* __restrict__ data, float* __restrict__ mu){
  int p = blockIdx.x*256 + threadIdx.x;
  if (p >= KCL*64) return;
  int k = p >> 6, f = p & 63;
  mu[p] = data[(size_t)k*(NN/KCL)*64 + f];   // init_idx = k*(N//K)
}

__global__ __launch_bounds__(128) void k_cluster_accum(const float* __restrict__ data,
    const float* __restrict__ mu, float* csum, float* cr, const int* nit, int iter)
{
  if (iter >= nit[0]) return;
  __shared__ float dt[128][65];
  __shared__ float rl[128][KCL];
  __shared__ float ms[KCL*64];
  int tid = threadIdx.x;
  int rowbase = blockIdx.x*128;
  for (int j=tid; j<KCL*64; j+=128) ms[j] = mu[j];
  for (int j=tid; j<128*64; j+=128){
    int rr = j>>6, f = j&63;
    int row = rowbase + rr;
    dt[rr][f] = (row<NN) ? data[(size_t)row*64+f] : 0.f;
  }
  __syncthreads();
  {
    int row = rowbase + tid;
    float dot[KCL];
    #pragma unroll
    for (int k2=0;k2<KCL;k2++) dot[k2]=0.f;
    for (int f=0; f<64; f++){
      float a = dt[tid][f];
      #pragma unroll
      for (int k2=0;k2<KCL;k2++) dot[k2] = fmaf(a, ms[k2*64+f], dot[k2]);
    }
    float m = -1e30f;
    #pragma unroll
    for (int k2=0;k2<KCL;k2++) m = fmaxf(m, 5.0f*dot[k2]);
    float s = 0.f, ev[KCL];
    #pragma unroll
    for (int k2=0;k2<KCL;k2++){ ev[k2] = expf(5.0f*dot[k2]-m); s += ev[k2]; }
    float inv = 1.0f/s;
    #pragma unroll
    for (int k2=0;k2<KCL;k2++) rl[tid][k2] = (row<NN) ? ev[k2]*inv : 0.f;
  }
  __syncthreads();
  for (int p=tid; p<KCL*64; p+=128){
    int k2 = p>>6, f = p&63;
    float acc = 0.f;
    for (int r2=0;r2<128;r2++) acc += rl[r2][k2]*dt[r2][f];
    unsafeAtomicAdd(&csum[p], acc);
  }
  if (tid < KCL){
    float acc = 0.f;
    for (int r2=0;r2<128;r2++) acc += rl[r2][tid];
    unsafeAtomicAdd(&cr[tid], acc);
  }
}

__global__ void k_mu_update(float* mu, float* csum, float* cr, const int* nit, int iter){
  if (iter >= nit[0]) return;
  int p = threadIdx.x;        // launched with exactly 640 threads
  float c = csum[p];
  float r = cr[p>>6];
  __syncthreads();
  mu[p] = c / r;
  csum[p] = 0.f;
  if (p < KCL) cr[p] = 0.f;
}

__global__ __launch_bounds__(128) void k_cluster_final(const float* __restrict__ data,
    const float* __restrict__ mu, void* __restrict__ out, const int* __restrict__ flag)
{
  __shared__ float dt[128][65];
  __shared__ float ms[KCL*64];
  int tid = threadIdx.x;
  int rowbase = blockIdx.x*128;
  for (int j=tid; j<KCL*64; j+=128) ms[j] = mu[j];
  for (int j=tid; j<128*64; j+=128){
    int rr = j>>6, f = j&63;
    int row = rowbase + rr;
    dt[rr][f] = (row<NN) ? data[(size_t)row*64+f] : 0.f;
  }
  __syncthreads();
  int row = rowbase + tid;
  if (row >= NN) return;
  int isbf = flag[0];
  float dot[KCL];
  #pragma unroll
  for (int k2=0;k2<KCL;k2++) dot[k2]=0.f;
  for (int f=0; f<64; f++){
    float a = dt[tid][f];
    #pragma unroll
    for (int k2=0;k2<KCL;k2++) dot[k2] = fmaf(a, ms[k2*64+f], dot[k2]);
  }
  float m = -1e30f;
  #pragma unroll
  for (int k2=0;k2<KCL;k2++) m = fmaxf(m, 5.0f*dot[k2]);
  float s = 0.f, ev[KCL];
  #pragma unroll
  for (int k2=0;k2<KCL;k2++){ ev[k2] = expf(5.0f*dot[k2]-m); s += ev[k2]; }
  float inv = 1.0f/s;
  #pragma unroll
  for (int k2=0;k2<KCL;k2++){
    stf(out, (size_t)D_OFF + (size_t)row*KCL + k2, dot[k2],     isbf);
    stf(out, (size_t)R_OFF + (size_t)row*KCL + k2, ev[k2]*inv,  isbf);
  }
}

__global__ void k_mu_out(const float* __restrict__ mu, void* __restrict__ out,
                         const int* __restrict__ flag){
  int p = blockIdx.x*256 + threadIdx.x;
  if (p < KCL*64) stf(out, MU_OFF + p, mu[p], flag[0]);
}

// ---------------- launch ----------------
extern "C" void kernel_launch(void* const* d_in, const int* in_sizes, int n_in,
                              void* d_out, int out_size, void* d_ws, size_t ws_size,
                              hipStream_t stream)
{
  const void* x   = d_in[0];
  const int*  ei  = (const int*)d_in[1];
  const int*  hv  = (const int*)d_in[2];
  const int*  he  = (const int*)d_in[3];
  const void* gW1 = d_in[4];
  const void* gb1 = d_in[5];
  const void* gW2 = d_in[6];
  const void* gb2 = d_in[7];
  const void* hW1 = d_in[8];
  const void* hb1 = d_in[9];
  const void* hW2 = d_in[10];
  const void* hb2 = d_in[11];
  const int*  nit = (const int*)d_in[12];

  float* ws = (float*)d_ws;
  size_t o = 0;
  u16*   xb  = (u16*)(ws + o); o += (size_t)NP*128;   // x bf16 NP x 256
  u16*   BAb = (u16*)(ws + o); o += (size_t)NP*64;    // GEMM out bf16 NP x 128
  u16*   BBb = (u16*)(ws + o); o += (size_t)NP*64;    // x1 bf16; later dataf f32
  u16*   BCb = (u16*)(ws + o); o += (size_t)NP*64;    // x3 bf16
  u16*   BDb = (u16*)(ws + o); o += (size_t)NEH*64;   // e_feat bf16 NEH x 128
  u16*  gW1t = (u16*)(ws + o); o += 16384;
  u16*  hW1t = (u16*)(ws + o); o += 16384;
  u16*  gW2t = (u16*)(ws + o); o += 4096;
  u16*  hW2t = (u16*)(ws + o); o += 4096;
  float* gb1f = ws + o; o += 128;
  float* hb1f = ws + o; o += 128;
  float* gb2f = ws + o; o += 64;
  float* hb2f = ws + o; o += 64;
  float* dinv = ws + o; o += 50048;
  float* invv = ws + o; o += 50048;
  float* inve = ws + o; o += 10048;
  float* mu   = ws + o; o += 640;
  float* csum = ws + o; o += 640;
  float* cr   = ws + o; o += 64;
  int*   dflg = (int*)(ws + o); o += 16;
  float* x2f   = (float*)xb;                 // aliases (xb dead by then)
  float* x4f   = (float*)xb + (size_t)NP*64;
  float* dataf = (float*)BBb;                // alias (BBb dead by then)
  // int region (CSR)
  int* ib = (int*)(ws + o);
  size_t io = 0;
  int* cg    = ib + io; io += NN;
  int* cv    = ib + io; io += NN;
  int* ce    = ib + io; io += NEH + 48;
  int* rp_g  = ib + io; io += NN;
  int* rp_v  = ib + io; io += NN;
  int* rp_e  = ib + io; io += NEH + 48;
  int* csr_g = ib + io; io += EE;
  int* csr_e = ib + io; io += NINC;
  int* csr_v = ib + io; io += NINC;
  int* bs_g  = ib + io; io += 256;
  int* bs_v  = ib + io; io += 256;
  int* bs_e  = ib + io; io += 256;
  u32* Hg = (u32*)(ib + io); io += 512*6250;     // 12.8MB
  u32* Hv = (u32*)(ib + io); io += 512*6250;     // 12.8MB
  u32* He = (u32*)(ib + io); io += 128*5000;     // 2.56MB

  const int* srcp = ei;
  const int* dstp = ei + EE;
  dim3 B(256);
  const int NBP = (NP + 255)/256;

  // dtype detection + input prep
  k_detect<<<dim3(1), B, 0, stream>>>((const u16*)x, dflg);
  k_aconv<<<dim3(12500), B, 0, stream>>>(x, xb, dflg);
  k_wprep<<<dim3(128), B, 0, stream>>>(gW1, hW1, gW2, hW2, gb1, hb1, gb2, hb2,
                                       gW1t, hW1t, gW2t, hW2t,
                                       gb1f, hb1f, gb2f, hb2f, dflg);

  // ---- atomic-free CSR build (8x6250 / 2x5000 ranges, 64 chunks) ----
  k_hist2<6250,64><<<dim3(512), B, 0, stream>>>(dstp, Hg, 12500);  // gcn by dst
  k_hist2<6250,64><<<dim3(512), B, 0, stream>>>(hv,   Hv, 3125);   // hg by vertex
  k_hist2<5000,64><<<dim3(128), B, 0, stream>>>(he,   He, 3125);   // hg by hyperedge
  k_hscan2<6250,64,8><<<dim3(196), B, 0, stream>>>(Hg, cg);
  k_hscan2<6250,64,8><<<dim3(196), B, 0, stream>>>(Hv, cv);
  k_hscan2<5000,64,2><<<dim3(40),  B, 0, stream>>>(He, ce);
  k_invs<<<dim3(NBP), B, 0, stream>>>(cg, cv, ce, dinv, invv, inve);
  k_scan1_all<<<dim3(432), B, 0, stream>>>(cg, cv, ce, rp_g, rp_v, rp_e, bs_g, bs_v, bs_e);
  k_scan2_all<<<dim3(3),   B, 0, stream>>>(bs_g, bs_v, bs_e);
  k_scan3_all<<<dim3(432), B, 0, stream>>>(rp_g, rp_v, rp_e, bs_g, bs_v, bs_e);
  k_fill3<6250,64><<<dim3(512), B, 0, stream>>>(dstp, srcp, Hg, rp_g, csr_g, 12500);
  k_fill3<6250,64><<<dim3(512), B, 0, stream>>>(hv,   he,   Hv, rp_v, csr_v, 3125);
  k_fill3<5000,64><<<dim3(128), B, 0, stream>>>(he,   hv,   He, rp_e, csr_e, 3125);

  const int NB = NP/64;                 // 782 MFMA blocks
  // ---- GCN layer 1: BAb = (x@gW1)*dinv[row] ; x1 = gather+gb1, relu ----
  k_gemm_mfma<256,128><<<dim3(NB), B, 0, stream>>>(xb, gW1t, nullptr, dinv, BAb, 0);
  k_gather<128,true,true><<<dim3(NN/4), B, 0, stream>>>(rp_g, cg, csr_g, dinv,
                                                        BAb, gb1f, BBb, 1);
  // ---- HGNNP layer 1 ----
  k_gemm_mfma<256,128><<<dim3(NB), B, 0, stream>>>(xb, hW1t, hb1f, nullptr, BAb, 0);
  k_gather<128,true,false><<<dim3(NEH/4), B, 0, stream>>>(rp_e, ce, csr_e, inve,
                                                          BAb, nullptr, BDb, 0);
  k_gather<128,true,false><<<dim3(NN/4), B, 0, stream>>>(rp_v, cv, csr_v, invv,
                                                         BDb, nullptr, BCb, 1);
  // ---- GCN layer 2 ----
  k_gemm_mfma<128,64><<<dim3(NB), B, 0, stream>>>(BBb, gW2t, nullptr, dinv, BAb, 0);
  k_gather<64,false,true><<<dim3(NN/4), B, 0, stream>>>(rp_g, cg, csr_g, dinv,
                                                        BAb, gb2f, x2f, 0);
  // ---- HGNNP layer 2 ----
  k_gemm_mfma<128,64><<<dim3(NB), B, 0, stream>>>(BCb, hW2t, hb2f, nullptr, BAb, 0);
  k_gather<64,true,false><<<dim3(NEH/4), B, 0, stream>>>(rp_e, ce, csr_e, inve,
                                                         BAb, nullptr, BDb, 0);
  k_gather<64,false,false><<<dim3(NN/4), B, 0, stream>>>(rp_v, cv, csr_v, invv,
                                                         BDb, nullptr, x4f, 0);

  // ---- embeds + normalized rows -> dataf ----
  k_embeds<<<dim3((NN+3)/4), B, 0, stream>>>(x2f, x4f, d_out, dataf, dflg);

  // ---- clustering ----
  k_mu_init<<<dim3(3), B, 0, stream>>>(dataf, mu);
  hipMemsetAsync(csum, 0, (640+64)*4, stream);
  const int CB = (NN + 127)/128;
  for (int it = 0; it < 4; ++it){   // gated by iter < *num_iter (setup: 1)
    k_cluster_accum<<<dim3(CB), dim3(128), 0, stream>>>(dataf, mu, csum, cr, nit, it);
    k_mu_update    <<<dim3(1),  dim3(640), 0, stream>>>(mu, csum, cr, nit, it);
  }
  k_cluster_final<<<dim3(CB), dim3(128), 0, stream>>>(dataf, mu, d_out, dflg);
  k_mu_out       <<<dim3(3),  B, 0, stream>>>(mu, d_out, dflg);
}

// Round 13
// 380.494 us; speedup vs baseline: 1.0294x; 1.0294x over previous
//
#include <hip/hip_runtime.h>
#include <hip/hip_bf16.h>

// HGNNP_GCN + ClusterNet forward, MI355X (round 13 = round 12 resubmit after
// infra failure).
// R10/R11: k_fill3 flat at 46-47us across 4x occupancy change -> scattered-
// write bound (WRITE 26.5MB for 3.2MB payload; cross-XCD line ping-pong in a
// shared csr window). This round: two-pass bucket sort. Pass A partitions
// edges into 250 coarse buckets as packed u32 (lk<<16|val) with per-(chunk,
// bucket) exclusive contiguous writes; pass B sorts each bucket inside one
// block, emitting cnt/rp for free and scattering csr within a private ~13KB
// window (L1-resident). hscan + global rp scans deleted.

#define NN   50000   // nodes (= 250*200)
#define NP   50048   // padded rows (782 * 64)
#define EE   800000  // directed edges (= 128*6250)
#define NINC 200000  // incidence entries (= 64*3125)
#define NEH  10000   // hyperedges (= 250*40)
#define KCL  10      // clusters

// output element offsets (flat concat: mu | r | embeds | dist)
#define MU_OFF  0
#define R_OFF   640
#define EMB_OFF 500640
#define D_OFF   3700640

typedef __hip_bfloat16 bf16;
typedef unsigned short u16;
typedef unsigned int   u32;
typedef __attribute__((ext_vector_type(8))) short short8;
typedef __attribute__((ext_vector_type(4))) float f32x4;

__device__ __forceinline__ float b2f(bf16 v){ return __bfloat162float(v); }
__device__ __forceinline__ float us2f(u16 u){ return __uint_as_float(((unsigned)u) << 16); }
__device__ __forceinline__ u16 f2bu(float f){
  unsigned u = __float_as_uint(f);
  return (u16)((u + 0x7fffu + ((u >> 16) & 1u)) >> 16);   // RNE
}
__device__ __forceinline__ bf16 f2b(float f){
  u16 r = f2bu(f);
  bf16 h;
  reinterpret_cast<u16&>(h) = r;
  return h;
}
__device__ __forceinline__ float ldf(const void* p, size_t i, int isbf){
  return isbf ? b2f(((const bf16*)p)[i]) : ((const float*)p)[i];
}
__device__ __forceinline__ void stf(void* p, size_t i, float v, int isbf){
  if (isbf) ((bf16*)p)[i] = f2b(v);
  else      ((float*)p)[i] = v;
}

// ---------------- dtype detector ----------------
__global__ void k_detect(const u16* __restrict__ xr, int* flag){
  __shared__ int bad;
  if (threadIdx.x == 0) bad = 0;
  __syncthreads();
  for (int i = threadIdx.x; i < 4096; i += 256){
    int e = (xr[i] >> 7) & 0xFF;
    if (e >= 0xEF) bad = 1;     // f32 low-halves have random exponents
  }
  __syncthreads();
  if (threadIdx.x == 0) *flag = bad ? 0 : 1;   // 1 = bf16, 0 = f32
}

// ---------------- input prep ----------------
__global__ void k_aconv(const void* __restrict__ x, u16* __restrict__ xb,
                        const int* __restrict__ flag){
  int i = blockIdx.x*256 + threadIdx.x;      // one ushort4 (4 elems)
  const int n4 = NN*256/4;
  if (i >= n4) return;
  ushort4 o;
  if (flag[0]){
    o = ((const ushort4*)x)[i];
  } else {
    float4 v = ((const float4*)x)[i];
    o = make_ushort4(f2bu(v.x), f2bu(v.y), f2bu(v.z), f2bu(v.w));
  }
  ((ushort4*)xb)[i] = o;
}

__global__ void k_wprep(const void* gW1, const void* hW1, const void* gW2, const void* hW2,
                        const void* gb1, const void* hb1, const void* gb2, const void* hb2,
                        u16* gW1t, u16* hW1t, u16* gW2t, u16* hW2t,
                        float* gb1f, float* hb1f, float* gb2f, float* hb2f,
                        const int* __restrict__ flag){
  const int isbf = flag[0];
  int i = blockIdx.x*256 + threadIdx.x;
  if (i < 256*128){                    // Wt[n][k] = W[k][n], 128x256
    int n = i >> 8, k = i & 255;
    gW1t[i] = f2bu(ldf(gW1, (size_t)k*128 + n, isbf));
    hW1t[i] = f2bu(ldf(hW1, (size_t)k*128 + n, isbf));
  }
  if (i < 64*128){                     // 64x128
    int n = i >> 7, k = i & 127;
    gW2t[i] = f2bu(ldf(gW2, (size_t)k*64 + n, isbf));
    hW2t[i] = f2bu(ldf(hW2, (size_t)k*64 + n, isbf));
  }
  if (i < 128){ gb1f[i] = ldf(gb1,i,isbf); hb1f[i] = ldf(hb1,i,isbf); }
  if (i < 64) { gb2f[i] = ldf(gb2,i,isbf); hb2f[i] = ldf(hb2,i,isbf); }
}

// ---------------- two-pass bucket CSR build ----------------
// NBKT coarse buckets of NPB keys each. Pass A: per-chunk bucket histogram.
template<int NBKT, int NPB>
__global__ __launch_bounds__(256) void k_histA(const int* __restrict__ key,
                                               int* __restrict__ HA, int chunk){
  __shared__ u32 hist[NBKT];
  for (int i = threadIdx.x; i < NBKT; i += 256) hist[i] = 0;
  __syncthreads();
  int base = blockIdx.x*chunk;
  for (int i = threadIdx.x; i < chunk; i += 256)
    atomicAdd(&hist[key[base+i]/NPB], 1u);
  __syncthreads();
  int* out = HA + blockIdx.x*NBKT;
  for (int i = threadIdx.x; i < NBKT; i += 256) out[i] = (int)hist[i];
}

// per-bucket prefix over chunks (in place) + bucket starts bs[0..250]
__global__ void k_scanA_all(int* HAg, int* HAv, int* HAe,
                            int* bsg, int* bsv, int* bse){
  int* HA; int* bs; int nch;
  if (blockIdx.x == 0){ HA = HAg; bs = bsg; nch = 128; }
  else if (blockIdx.x == 1){ HA = HAv; bs = bsv; nch = 64; }
  else { HA = HAe; bs = bse; nch = 64; }
  __shared__ int s[256];
  int t = threadIdx.x;
  int run = 0;
  if (t < 250){
    for (int c = 0; c < nch; ++c){
      int v = HA[c*250 + t];
      HA[c*250 + t] = run;       // prefix-before-chunk
      run += v;
    }
  }
  int own = (t < 250) ? run : 0;
  s[t] = own; __syncthreads();
  #pragma unroll
  for (int off = 1; off < 256; off <<= 1){
    int add = (t >= off) ? s[t-off] : 0;
    __syncthreads();
    s[t] += add;
    __syncthreads();
  }
  if (t < 250) bs[t] = s[t] - own;   // exclusive bucket start
  if (t == 255) bs[250] = s[255];    // total
}

// Pass A fill: partition into buckets as packed u32 (lk<<16 | val).
// Writes per (chunk,bucket) are contiguous & exclusive -> no line sharing.
template<int NBKT, int NPB>
__global__ __launch_bounds__(256) void k_fillA(const int* __restrict__ key,
    const int* __restrict__ val, const int* __restrict__ HA,
    const int* __restrict__ bs, u32* __restrict__ packed, int chunk){
  __shared__ u32 cur[NBKT];
  const int* pre = HA + blockIdx.x*NBKT;
  for (int i = threadIdx.x; i < NBKT; i += 256) cur[i] = (u32)(bs[i] + pre[i]);
  __syncthreads();
  int base = blockIdx.x*chunk;
  for (int i = threadIdx.x; i < chunk; i += 256){
    int k = key[base+i];
    int b = k / NPB;
    u32 pos = atomicAdd(&cur[b], 1u);
    packed[pos] = ((u32)(k - b*NPB) << 16) | (u32)val[base+i];
  }
}

// Pass B: one block per bucket. Fine hist + scan in LDS -> cnt, rp for free;
// csr scatter confined to this bucket's private window (~13KB, L1-resident).
template<int NPB>
__global__ __launch_bounds__(256) void k_fillB(const u32* __restrict__ packed,
    const int* __restrict__ bs, int* __restrict__ csr,
    int* __restrict__ cnt, int* __restrict__ rp){
  __shared__ u32 hist[NPB];
  __shared__ int s[256];
  __shared__ u32 cur[NPB];
  const int b = blockIdx.x;
  const int s0 = bs[b], m = bs[b+1] - s0;
  const int t = threadIdx.x;
  for (int i = t; i < NPB; i += 256) hist[i] = 0;
  __syncthreads();
  for (int i = t; i < m; i += 256)
    atomicAdd(&hist[packed[s0+i] >> 16], 1u);
  __syncthreads();
  int own = (t < NPB) ? (int)hist[t] : 0;
  s[t] = own; __syncthreads();
  #pragma unroll
  for (int off = 1; off < 256; off <<= 1){
    int add = (t >= off) ? s[t-off] : 0;
    __syncthreads();
    s[t] += add;
    __syncthreads();
  }
  if (t < NPB){
    int excl = s[t] - own;
    cnt[b*NPB + t] = own;
    rp[b*NPB + t]  = s0 + excl;
    cur[t] = (u32)(s0 + excl);
  }
  __syncthreads();
  for (int i = t; i < m; i += 256){
    u32 p = packed[s0+i];
    u32 pos = atomicAdd(&cur[p >> 16], 1u);
    csr[pos] = (int)(p & 0xffffu);
  }
}

__global__ void k_invs(const int* __restrict__ cg, const int* __restrict__ cv,
                       const int* __restrict__ ce,
                       float* dinv, float* invv, float* inve){
  int i = blockIdx.x*256 + threadIdx.x;
  if (i < NN){
    float d = 1.0f + (float)cg[i];     // self-loop included
    dinv[i] = rsqrtf(d);
    invv[i] = 1.0f / fmaxf((float)cv[i], 1.0f);
  } else if (i < NP){
    dinv[i] = 0.f;                     // pad rows
  }
  if (i < NEH) inve[i] = 1.0f / fmaxf((float)ce[i], 1.0f);
}

// ---------------- MFMA GEMM ----------------
template<int KDIM, int NCOL>
__global__ __launch_bounds__(256) void k_gemm_mfma(
    const u16* __restrict__ A, const u16* __restrict__ Wt,
    const float* __restrict__ bias, const float* __restrict__ rowscale,
    u16* __restrict__ C, int relu)
{
  constexpr int NT  = NCOL/16;
  constexpr int LDA = 40;
  __shared__ __align__(16) u16 Asl[64][LDA];
  __shared__ __align__(16) u16 Wsl[NCOL][LDA];
  const int tid  = threadIdx.x;
  const int wave = tid >> 6, lane = tid & 63;
  const int l15 = lane & 15, l4 = lane >> 4;
  const int row0 = blockIdx.x * 64;
  const int ar = tid >> 2, aq = tid & 3;
  constexpr int NW = NCOL*4/256;

  f32x4 acc[NT] = {};

  for (int kk = 0; kk < KDIM; kk += 32){
    {
      uint4 v = *(const uint4*)(A + (size_t)(row0 + ar)*KDIM + kk + aq*8);
      *(uint4*)&Asl[ar][aq*8] = v;
    }
    #pragma unroll
    for (int w2 = 0; w2 < NW; ++w2){
      int c = tid + w2*256;
      int n = c >> 2, q = c & 3;
      uint4 v = *(const uint4*)(Wt + (size_t)n*KDIM + kk + q*8);
      *(uint4*)&Wsl[n][q*8] = v;
    }
    __syncthreads();
    short8 af = *(const short8*)&Asl[wave*16 + l15][l4*8];
    #pragma unroll
    for (int t = 0; t < NT; ++t){
      short8 bf = *(const short8*)&Wsl[t*16 + l15][l4*8];
      acc[t] = __builtin_amdgcn_mfma_f32_16x16x32_bf16(af, bf, acc[t], 0, 0, 0);
    }
    __syncthreads();
  }

  #pragma unroll
  for (int t = 0; t < NT; ++t){
    int gcol = t*16 + l15;
    float b = bias ? bias[gcol] : 0.f;
    #pragma unroll
    for (int e = 0; e < 4; ++e){
      int grow = row0 + wave*16 + l4*4 + e;
      float v = acc[t][e] + b;
      if (relu) v = fmaxf(v, 0.f);
      if (rowscale) v *= rowscale[grow];
      C[(size_t)grow*NCOL + gcol] = f2bu(v);
    }
  }
}

// ---------------- unified gather: one wave per dst row ----------------
template<int F, bool OUTBF, bool SELF>
__global__ __launch_bounds__(256) void k_gather(
    const int* __restrict__ rp, const int* __restrict__ cnt,
    const int* __restrict__ csr, const float* __restrict__ scale,
    const u16* __restrict__ h, const float* __restrict__ bias,
    void* __restrict__ out, int relu)
{
  const int wave = threadIdx.x >> 6, lane = threadIdx.x & 63;
  const int d = blockIdx.x*4 + wave;
  const int k0 = rp[d], n = cnt[d];

  if constexpr (F == 128){
    const uint* h32 = (const uint*)h;
    float a0=0,a1=0,b0=0,b1=0,c0=0,c1=0,e0=0,e1=0;
    if (SELF){
      uint v = h32[(size_t)d*64 + lane];
      a0 = us2f((u16)v); a1 = us2f((u16)(v>>16));
    }
    for (int base = 0; base < n; base += 64){
      int mm = n - base; if (mm > 64) mm = 64;
      int idx = (lane < mm) ? csr[k0 + base + lane] : 0;
      int jj = 0;
      for (; jj + 4 <= mm; jj += 4){
        int s0=__shfl(idx,jj), s1=__shfl(idx,jj+1), s2=__shfl(idx,jj+2), s3=__shfl(idx,jj+3);
        uint v0 = h32[(size_t)s0*64 + lane];
        uint v1 = h32[(size_t)s1*64 + lane];
        uint v2 = h32[(size_t)s2*64 + lane];
        uint v3 = h32[(size_t)s3*64 + lane];
        a0 += us2f((u16)v0); a1 += us2f((u16)(v0>>16));
        b0 += us2f((u16)v1); b1 += us2f((u16)(v1>>16));
        c0 += us2f((u16)v2); c1 += us2f((u16)(v2>>16));
        e0 += us2f((u16)v3); e1 += us2f((u16)(v3>>16));
      }
      for (; jj < mm; ++jj){
        int s = __shfl(idx, jj);
        uint v = h32[(size_t)s*64 + lane];
        a0 += us2f((u16)v); a1 += us2f((u16)(v>>16));
      }
    }
    float sc = scale[d];
    float o0 = ((a0+b0)+(c0+e0))*sc;
    float o1 = ((a1+b1)+(c1+e1))*sc;
    if (bias){ o0 += bias[lane*2]; o1 += bias[lane*2+1]; }
    if (relu){ o0 = fmaxf(o0,0.f); o1 = fmaxf(o1,0.f); }
    if (OUTBF){
      ((uint*)out)[(size_t)d*64 + lane] = (uint)f2bu(o0) | ((uint)f2bu(o1) << 16);
    } else {
      ((float2*)out)[(size_t)d*64 + lane] = make_float2(o0, o1);
    }
  } else { // F == 64
    float a=0,b=0,c=0,e=0;
    if (SELF) a = us2f(h[(size_t)d*64 + lane]);
    for (int base = 0; base < n; base += 64){
      int mm = n - base; if (mm > 64) mm = 64;
      int idx = (lane < mm) ? csr[k0 + base + lane] : 0;
      int jj = 0;
      for (; jj + 4 <= mm; jj += 4){
        int s0=__shfl(idx,jj), s1=__shfl(idx,jj+1), s2=__shfl(idx,jj+2), s3=__shfl(idx,jj+3);
        a += us2f(h[(size_t)s0*64 + lane]);
        b += us2f(h[(size_t)s1*64 + lane]);
        c += us2f(h[(size_t)s2*64 + lane]);
        e += us2f(h[(size_t)s3*64 + lane]);
      }
      for (; jj < mm; ++jj){
        int s = __shfl(idx, jj);
        a += us2f(h[(size_t)s*64 + lane]);
      }
    }
    float o = ((a+b)+(c+e))*scale[d];
    if (bias) o += bias[lane];
    if (relu) o = fmaxf(o, 0.f);
    if (OUTBF) ((u16*)out)[(size_t)d*64 + lane] = f2bu(o);
    else       ((float*)out)[(size_t)d*64 + lane] = o;
  }
}

// ---------------- embeds + row normalize ----------------
__global__ void k_embeds(const float* __restrict__ x2, const float* __restrict__ x4,
                         void* __restrict__ out, float* __restrict__ data,
                         const int* __restrict__ flag){
  int row  = blockIdx.x*4 + (threadIdx.x >> 6);
  int lane = threadIdx.x & 63;
  if (row >= NN) return;
  size_t idx = (size_t)row*64 + lane;
  float v = 0.5f*(x2[idx] + x4[idx]);
  float ss = v*v;
  #pragma unroll
  for (int off=32; off>0; off>>=1) ss += __shfl_xor(ss, off);
  float inv = rsqrtf(ss);
  data[idx] = v*inv;
  stf(out, EMB_OFF + idx, v, flag[0]);
}

// ---------------- clustering ----------------
__global__ void k_mu_init(const float* __restrict__ data, float* __restrict__ mu){
  int p = blockIdx.x*256 + threadIdx.x;
  if (p >= KCL*64) return;
  int k = p >> 6, f = p & 63;
  mu[p] = data[(size_t)k*(NN/KCL)*64 + f];   // init_idx = k*(N//K)
}

__global__ __launch_bounds__(128) void k_cluster_accum(const float* __restrict__ data,
    const float* __restrict__ mu, float* csum, float* cr, const int* nit, int iter)
{
  if (iter >= nit[0]) return;
  __shared__ float dt[128][65];
  __shared__ float rl[128][KCL];
  __shared__ float ms[KCL*64];
  int tid = threadIdx.x;
  int rowbase = blockIdx.x*128;
  for (int j=tid; j<KCL*64; j+=128) ms[j] = mu[j];
  for (int j=tid; j<128*64; j+=128){
    int rr = j>>6, f = j&63;
    int row = rowbase + rr;
    dt[rr][f] = (row<NN) ? data[(size_t)row*64+f] : 0.f;
  }
  __syncthreads();
  {
    int row = rowbase + tid;
    float dot[KCL];
    #pragma unroll
    for (int k2=0;k2<KCL;k2++) dot[k2]=0.f;
    for (int f=0; f<64; f++){
      float a = dt[tid][f];
      #pragma unroll
      for (int k2=0;k2<KCL;k2++) dot[k2] = fmaf(a, ms[k2*64+f], dot[k2]);
    }
    float m = -1e30f;
    #pragma unroll
    for (int k2=0;k2<KCL;k2++) m = fmaxf(m, 5.0f*dot[k2]);
    float s = 0.f, ev[KCL];
    #pragma unroll
    for (int k2=0;k2<KCL;k2++){ ev[k2] = expf(5.0f*dot[k2]-m); s += ev[k2]; }
    float inv = 1.0f/s;
    #pragma unroll
    for (int k2=0;k2<KCL;k2++) rl[tid][k2] = (row<NN) ? ev[k2]*inv : 0.f;
  }
  __syncthreads();
  for (int p=tid; p<KCL*64; p+=128){
    int k2 = p>>6, f = p&63;
    float acc = 0.f;
    for (int r2=0;r2<128;r2++) acc += rl[r2][k2]*dt[r2][f];
    unsafeAtomicAdd(&csum[p], acc);
  }
  if (tid < KCL){
    float acc = 0.f;
    for (int r2=0;r2<128;r2++) acc += rl[r2][tid];
    unsafeAtomicAdd(&cr[tid], acc);
  }
}

__global__ void k_mu_update(float* mu, float* csum, float* cr, const int* nit, int iter){
  if (iter >= nit[0]) return;
  int p = threadIdx.x;        // launched with exactly 640 threads
  float c = csum[p];
  float r = cr[p>>6];
  __syncthreads();
  mu[p] = c / r;
  csum[p] = 0.f;
  if (p < KCL) cr[p] = 0.f;
}

__global__ __launch_bounds__(128) void k_cluster_final(const float* __restrict__ data,
    const float* __restrict__ mu, void* __restrict__ out, const int* __restrict__ flag)
{
  __shared__ float dt[128][65];
  __shared__ float ms[KCL*64];
  int tid = threadIdx.x;
  int rowbase = blockIdx.x*128;
  for (int j=tid; j<KCL*64; j+=128) ms[j] = mu[j];
  for (int j=tid; j<128*64; j+=128){
    int rr = j>>6, f = j&63;
    int row = rowbase + rr;
    dt[rr][f] = (row<NN) ? data[(size_t)row*64+f] : 0.f;
  }
  __syncthreads();
  int row = rowbase + tid;
  if (row >= NN) return;
  int isbf = flag[0];
  float dot[KCL];
  #pragma unroll
  for (int k2=0;k2<KCL;k2++) dot[k2]=0.f;
  for (int f=0; f<64; f++){
    float a = dt[tid][f];
    #pragma unroll
    for (int k2=0;k2<KCL;k2++) dot[k2] = fmaf(a, ms[k2*64+f], dot[k2]);
  }
  float m = -1e30f;
  #pragma unroll
  for (int k2=0;k2<KCL;k2++) m = fmaxf(m, 5.0f*dot[k2]);
  float s = 0.f, ev[KCL];
  #pragma unroll
  for (int k2=0;k2<KCL;k2++){ ev[k2] = expf(5.0f*dot[k2]-m); s += ev[k2]; }
  float inv = 1.0f/s;
  #pragma unroll
  for (int k2=0;k2<KCL;k2++){
    stf(out, (size_t)D_OFF + (size_t)row*KCL + k2, dot[k2],     isbf);
    stf(out, (size_t)R_OFF + (size_t)row*KCL + k2, ev[k2]*inv,  isbf);
  }
}

__global__ void k_mu_out(const float* __restrict__ mu, void* __restrict__ out,
                         const int* __restrict__ flag){
  int p = blockIdx.x*256 + threadIdx.x;
  if (p < KCL*64) stf(out, MU_OFF + p, mu[p], flag[0]);
}

// ---------------- launch ----------------
extern "C" void kernel_launch(void* const* d_in, const int* in_sizes, int n_in,
                              void* d_out, int out_size, void* d_ws, size_t ws_size,
                              hipStream_t stream)
{
  const void* x   = d_in[0];
  const int*  ei  = (const int*)d_in[1];
  const int*  hv  = (const int*)d_in[2];
  const int*  he  = (const int*)d_in[3];
  const void* gW1 = d_in[4];
  const void* gb1 = d_in[5];
  const void* gW2 = d_in[6];
  const void* gb2 = d_in[7];
  const void* hW1 = d_in[8];
  const void* hb1 = d_in[9];
  const void* hW2 = d_in[10];
  const void* hb2 = d_in[11];
  const int*  nit = (const int*)d_in[12];

  float* ws = (float*)d_ws;
  size_t o = 0;
  u16*   xb  = (u16*)(ws + o); o += (size_t)NP*128;   // x bf16 NP x 256
  u16*   BAb = (u16*)(ws + o); o += (size_t)NP*64;    // GEMM out bf16 NP x 128
  u16*   BBb = (u16*)(ws + o); o += (size_t)NP*64;    // x1 bf16; later dataf f32
  u16*   BCb = (u16*)(ws + o); o += (size_t)NP*64;    // x3 bf16
  u16*   BDb = (u16*)(ws + o); o += (size_t)NEH*64;   // e_feat bf16 NEH x 128
  u16*  gW1t = (u16*)(ws + o); o += 16384;
  u16*  hW1t = (u16*)(ws + o); o += 16384;
  u16*  gW2t = (u16*)(ws + o); o += 4096;
  u16*  hW2t = (u16*)(ws + o); o += 4096;
  float* gb1f = ws + o; o += 128;
  float* hb1f = ws + o; o += 128;
  float* gb2f = ws + o; o += 64;
  float* hb2f = ws + o; o += 64;
  float* dinv = ws + o; o += 50048;
  float* invv = ws + o; o += 50048;
  float* inve = ws + o; o += 10048;
  float* mu   = ws + o; o += 640;
  float* csum = ws + o; o += 640;
  float* cr   = ws + o; o += 64;
  int*   dflg = (int*)(ws + o); o += 16;
  float* x2f   = (float*)xb;                 // aliases (xb dead by then)
  float* x4f   = (float*)xb + (size_t)NP*64;
  float* dataf = (float*)BBb;                // alias (BBb dead by then)
  // int region (CSR)
  int* ib = (int*)(ws + o);
  size_t io = 0;
  int* cg    = ib + io; io += NN;
  int* cv    = ib + io; io += NN;
  int* ce    = ib + io; io += NEH + 48;
  int* rp_g  = ib + io; io += NN;
  int* rp_v  = ib + io; io += NN;
  int* rp_e  = ib + io; io += NEH + 48;
  int* csr_g = ib + io; io += EE;
  int* csr_e = ib + io; io += NINC;
  int* csr_v = ib + io; io += NINC;
  int* HAg   = ib + io; io += 128*250;
  int* HAv   = ib + io; io += 64*250;
  int* HAe   = ib + io; io += 64*250;
  int* bsg   = ib + io; io += 256;
  int* bsv   = ib + io; io += 256;
  int* bse   = ib + io; io += 256;
  u32* pg = (u32*)(ib + io); io += EE;      // packed buckets
  u32* pv = (u32*)(ib + io); io += NINC;
  u32* pe = (u32*)(ib + io); io += NINC;

  const int* srcp = ei;
  const int* dstp = ei + EE;
  dim3 B(256);
  const int NBP = (NP + 255)/256;

  // dtype detection + input prep
  k_detect<<<dim3(1), B, 0, stream>>>((const u16*)x, dflg);
  k_aconv<<<dim3(12500), B, 0, stream>>>(x, xb, dflg);
  k_wprep<<<dim3(128), B, 0, stream>>>(gW1, hW1, gW2, hW2, gb1, hb1, gb2, hb2,
                                       gW1t, hW1t, gW2t, hW2t,
                                       gb1f, hb1f, gb2f, hb2f, dflg);

  // ---- two-pass bucket CSR build (250 buckets) ----
  k_histA<250,200><<<dim3(128), B, 0, stream>>>(dstp, HAg, 6250);
  k_histA<250,200><<<dim3(64),  B, 0, stream>>>(hv,   HAv, 3125);
  k_histA<250, 40><<<dim3(64),  B, 0, stream>>>(he,   HAe, 3125);
  k_scanA_all<<<dim3(3), B, 0, stream>>>(HAg, HAv, HAe, bsg, bsv, bse);
  k_fillA<250,200><<<dim3(128), B, 0, stream>>>(dstp, srcp, HAg, bsg, pg, 6250);
  k_fillA<250,200><<<dim3(64),  B, 0, stream>>>(hv,   he,   HAv, bsv, pv, 3125);
  k_fillA<250, 40><<<dim3(64),  B, 0, stream>>>(he,   hv,   HAe, bse, pe, 3125);
  k_fillB<200><<<dim3(250), B, 0, stream>>>(pg, bsg, csr_g, cg, rp_g);
  k_fillB<200><<<dim3(250), B, 0, stream>>>(pv, bsv, csr_v, cv, rp_v);
  k_fillB< 40><<<dim3(250), B, 0, stream>>>(pe, bse, csr_e, ce, rp_e);
  k_invs<<<dim3(NBP), B, 0, stream>>>(cg, cv, ce, dinv, invv, inve);

  const int NB = NP/64;                 // 782 MFMA blocks
  // ---- GCN layer 1: BAb = (x@gW1)*dinv[row] ; x1 = gather+gb1, relu ----
  k_gemm_mfma<256,128><<<dim3(NB), B, 0, stream>>>(xb, gW1t, nullptr, dinv, BAb, 0);
  k_gather<128,true,true><<<dim3(NN/4), B, 0, stream>>>(rp_g, cg, csr_g, dinv,
                                                        BAb, gb1f, BBb, 1);
  // ---- HGNNP layer 1 ----
  k_gemm_mfma<256,128><<<dim3(NB), B, 0, stream>>>(xb, hW1t, hb1f, nullptr, BAb, 0);
  k_gather<128,true,false><<<dim3(NEH/4), B, 0, stream>>>(rp_e, ce, csr_e, inve,
                                                          BAb, nullptr, BDb, 0);
  k_gather<128,true,false><<<dim3(NN/4), B, 0, stream>>>(rp_v, cv, csr_v, invv,
                                                         BDb, nullptr, BCb, 1);
  // ---- GCN layer 2 ----
  k_gemm_mfma<128,64><<<dim3(NB), B, 0, stream>>>(BBb, gW2t, nullptr, dinv, BAb, 0);
  k_gather<64,false,true><<<dim3(NN/4), B, 0, stream>>>(rp_g, cg, csr_g, dinv,
                                                        BAb, gb2f, x2f, 0);
  // ---- HGNNP layer 2 ----
  k_gemm_mfma<128,64><<<dim3(NB), B, 0, stream>>>(BCb, hW2t, hb2f, nullptr, BAb, 0);
  k_gather<64,true,false><<<dim3(NEH/4), B, 0, stream>>>(rp_e, ce, csr_e, inve,
                                                         BAb, nullptr, BDb, 0);
  k_gather<64,false,false><<<dim3(NN/4), B, 0, stream>>>(rp_v, cv, csr_v, invv,
                                                         BDb, nullptr, x4f, 0);

  // ---- embeds + normalized rows -> dataf ----
  k_embeds<<<dim3((NN+3)/4), B, 0, stream>>>(x2f, x4f, d_out, dataf, dflg);

  // ---- clustering ----
  k_mu_init<<<dim3(3), B, 0, stream>>>(dataf, mu);
  hipMemsetAsync(csum, 0, (640+64)*4, stream);
  const int CB = (NN + 127)/128;
  for (int it = 0; it < 4; ++it){   // gated by iter < *num_iter (setup: 1)
    k_cluster_accum<<<dim3(CB), dim3(128), 0, stream>>>(dataf, mu, csum, cr, nit, it);
    k_mu_update    <<<dim3(1),  dim3(640), 0, stream>>>(mu, csum, cr, nit, it);
  }
  k_cluster_final<<<dim3(CB), dim3(128), 0, stream>>>(dataf, mu, d_out, dflg);
  k_mu_out       <<<dim3(3),  B, 0, stream>>>(mu, d_out, dflg);
}